// Round 16
// baseline (1473.993 us; speedup 1.0000x reference)
//
#include <hip/hip_runtime.h>
#include <math.h>

// ---------------------------------------------------------------------------
// Disentangler: 32 component-MLPs over sampled token rows + masked seg-pool.
// Round-16: algebraic split kept (pooled = hsum @ W2 + n_t*b2), but the
// segment-sum moved OFF gemm1 (r15's fused epilogue cost +250us): gemm1 is
// r12-exact (writes pre-swizzled bf16 h, 441us proven); a BW-bound
// hsum_kernel streams h in t-sorted order (perm built by dedup) with
// register accumulation + rare uniform flushes; gemm3 does hsum@W2 (M=16,
// bounded by one fp32 W2 read). gemm2's 137 GFLOP remain deleted.
// ---------------------------------------------------------------------------

typedef __attribute__((ext_vector_type(8))) short bf16x8;
typedef __attribute__((ext_vector_type(4))) short s16x4;
typedef __attribute__((ext_vector_type(4))) float f32x4;
typedef unsigned int u32;

constexpr int TT    = 16;
constexpr int TOKN  = 4096;
constexpr int DD    = 2048;
constexpr int HH    = 2048;
constexpr int CC    = 1024;
constexpr int LL    = 1000;
constexpr int NCOMP = 32;
constexpr int MP    = 1024;
constexpr int BMX = 256, BNX = 128;
constexpr int MTX  = MP / BMX;    // 4 m-tiles
constexpr int NT1 = HH / BNX;     // 16 n-tiles (gemm1)
constexpr int NT  = DD / 64;      // 32 K-tiles

__device__ __forceinline__ short f2bf(float f) {
  __bf16 h = (__bf16)f;
  return *reinterpret_cast<short*>(&h);
}
__device__ __forceinline__ float bf2f(short s) {
  union { unsigned u; float f; } v;
  v.u = ((unsigned)(unsigned short)s) << 16;
  return v.f;
}
// Row swizzle (period 64): data-granule g of a 64-elem chunk lives at slot
// g ^ swz(row). Identical layout in Ab, h, and the LDS tiles.
__device__ __forceinline__ int swz(int row) {
  return (row & 7) ^ ((row >> 3) & 7);
}
__device__ __forceinline__ int sw(int row, int gran) {   // short offset
  return (row << 6) + ((gran ^ swz(row)) << 3);
}
__device__ __forceinline__ void gl_lds16(const void* g, void* l) {
  __builtin_amdgcn_global_load_lds(
      (const __attribute__((address_space(1))) u32*)g,
      (__attribute__((address_space(3))) u32*)l, 16, 0, 0);
}

// ------------- dedup: keep-mask, per-t counts, t-sorted perm ---------------
__global__ void dedup_kernel(const int* __restrict__ ridx,
                             unsigned* __restrict__ bitmap,
                             int* __restrict__ perm,
                             int* __restrict__ counts) {
  __shared__ int info[MP];       // t (4b) | keep<<8
  __shared__ int cnt[TT];
  __shared__ int base[TT + 1];
  int comp = blockIdx.x;
  if (threadIdx.x < TT) cnt[threadIdx.x] = 0;
  __syncthreads();
  for (int l = threadIdx.x; l < MP; l += 256) {
    int v = 0;
    if (l < LL) {
      int r = ridx[comp * LL + l];
      unsigned bit = 1u << (r & 31);
      unsigned old = atomicOr(&bitmap[(comp << 10) + (r >> 5)], bit);
      int kv = (old & bit) ? 0 : 1;
      if (kv) atomicAdd(&cnt[r >> 11], 1);
      v = (r >> 11) | (kv << 8);
    }
    info[l] = v;
  }
  __syncthreads();
  if (threadIdx.x == 0) {
    int s = 0;
    for (int t = 0; t < TT; ++t) {
      base[t] = s; counts[comp * TT + t] = cnt[t]; s += cnt[t];
    }
    base[TT] = s;
  }
  __syncthreads();
  if (threadIdx.x < TT) {                 // 16 scanners, l-ascending (stable)
    int t = threadIdx.x, off = base[t];
    for (int l = 0; l < MP; ++l) {
      int v = info[l];
      if ((v >> 8) && (v & 15) == t) perm[(comp << 10) + off++] = l;
    }
  }
}

// --------------------------- gather: x rows -> pre-swizzled bf16 -----------
__global__ __launch_bounds__(256) void gather_kernel(
    const float* __restrict__ x, const int* __restrict__ ridx,
    short* __restrict__ Ab) {
  int bid = blockIdx.x;
  int comp = bid >> 7, rgrp = bid & 127;
  int t = threadIdx.x;
  int tr = t >> 5, tn = t & 31;
  int m = rgrp * 8 + tr;
  int mi = m < LL ? m : LL - 1;
  int r = ridx[comp * LL + mi];
  int tokoff = comp >= 16 ? TOKN / 2 : 0;
  const float* src = x + ((size_t)(r >> 11) * TOKN + (r & 2047) + tokoff) * DD;
  short* drow = Ab + ((size_t)(comp * MP + m)) * DD;
  int s_m = swz(m);
#pragma unroll
  for (int i = 0; i < 8; ++i) {
    int gi = tn + 32 * i;
    float4 f0 = *reinterpret_cast<const float4*>(src + gi * 8);
    float4 f1 = *reinterpret_cast<const float4*>(src + gi * 8 + 4);
    bf16x8 pk;
    pk[0]=f2bf(f0.x); pk[1]=f2bf(f0.y); pk[2]=f2bf(f0.z); pk[3]=f2bf(f0.w);
    pk[4]=f2bf(f1.x); pk[5]=f2bf(f1.y); pk[6]=f2bf(f1.z); pk[7]=f2bf(f1.w);
    int c = gi >> 3, g = gi & 7;
    *reinterpret_cast<bf16x8*>(&drow[c * 64 + ((g ^ s_m) << 3)]) = pk;
  }
}

// --------------------------- K-loop (r12, unchanged) -----------------------
template<int LDW>
__device__ __forceinline__ void kloop(
    const short* __restrict__ aBase,   // bf16 pre-swizzled rows, stride 2048
    const float* __restrict__ wBase,   // fp32 W [k][LDW] at col offset nt*BNX
    short* sm, f32x4 (&acc)[8][4],
    int wm, int wn, int lr, int lg, int tid) {
  const short* aSrc0 = aBase + (size_t)(tid >> 3) * 2048 + (tid & 7) * 8;
  int ldsA0 = tid * 8;
  int tn = tid & 31, tkb = tid >> 5, bn0 = tn * 4;
  const float* wCol = wBase + bn0;

  float4 brB[8];

  auto aglds = [&](int t, int buf) {
    short* l = sm + buf * 16384;
#pragma unroll
    for (int q = 0; q < 8; ++q)
      gl_lds16(aSrc0 + (size_t)q * 65536 + t * 64, l + ldsA0 + q * 2048);
  };
  auto bload = [&](int t) {
    const float* bb = wCol + (size_t)(t * 64 + tkb * 8) * LDW;
#pragma unroll
    for (int i = 0; i < 8; ++i)
      brB[i] = *reinterpret_cast<const float4*>(bb + (size_t)i * LDW);
  };
  auto bwrite = [&]() {
    short* Bs = sm + 32768;
#pragma unroll
    for (int j = 0; j < 4; ++j) {
      bf16x8 pk;
#pragma unroll
      for (int i = 0; i < 8; ++i) pk[i] = f2bf((&brB[i].x)[j]);
      *reinterpret_cast<bf16x8*>(&Bs[sw(bn0 + j, tkb)]) = pk;
    }
  };
  auto compute = [&](int d) {
    const short* A = sm + d * 16384;
    const short* B = sm + 32768;
#pragma unroll
    for (int kk = 0; kk < 2; ++kk) {
      bf16x8 af[8], bfr[4];
#pragma unroll
      for (int i = 0; i < 8; ++i)
        af[i] = *reinterpret_cast<const bf16x8*>(&A[sw(wm + i * 16 + lr, kk * 4 + lg)]);
#pragma unroll
      for (int j = 0; j < 4; ++j)
        bfr[j] = *reinterpret_cast<const bf16x8*>(&B[sw(wn + j * 16 + lr, kk * 4 + lg)]);
      __builtin_amdgcn_s_setprio(1);
#pragma unroll
      for (int i = 0; i < 8; ++i)
#pragma unroll
        for (int j = 0; j < 4; ++j)
          acc[i][j] = __builtin_amdgcn_mfma_f32_16x16x32_bf16(af[i], bfr[j], acc[i][j], 0, 0, 0);
      __builtin_amdgcn_s_setprio(0);
    }
  };

  bload(0);
  aglds(0, 0);
  bwrite();
  bload(1);
  aglds(1, 1);
  asm volatile("s_waitcnt lgkmcnt(0)" ::: "memory");
  __builtin_amdgcn_s_barrier();

#pragma unroll 1
  for (int t = 0; t < NT; ++t) {
    if (t < NT - 1) {
      asm volatile("s_waitcnt vmcnt(16)" ::: "memory");  // A(t) landed
    } else {
      asm volatile("s_waitcnt vmcnt(0)" ::: "memory");
    }
    __builtin_amdgcn_sched_barrier(0);
    compute(t & 1);
    __builtin_amdgcn_s_barrier();          // all waves done reading A(t), B(t)
    if (t + 1 < NT) {
      bwrite();                            // B(t+1) -> Bbuf (vmcnt(8) auto)
      if (t + 2 < NT) {
        bload(t + 2);                      // issued BEFORE aglds (ordering!)
        aglds(t + 2, t & 1);
      }
      asm volatile("s_waitcnt lgkmcnt(0)" ::: "memory");
      __builtin_amdgcn_s_barrier();
    }
  }
}

// --------------------------- GEMM1: h = gelu(x_sel @ W1 + b1) --------------
__global__ __launch_bounds__(256, 2) void gemm1_kernel(
    const float* __restrict__ nW1, const float* __restrict__ nb1,
    const float* __restrict__ eW1, const float* __restrict__ eb1,
    const short* __restrict__ Ab, short* __restrict__ hbuf) {
  __shared__ short smem[40960];   // 80 KB

  constexpr int NWG = NCOMP * MTX * NT1;   // 2048
  constexpr int CPX = NWG / 8;
  int b0 = blockIdx.x;
  int lb = (b0 & 7) * CPX + (b0 >> 3);     // XCD-chunked (T1), bijective
  int comp = lb / (MTX * NT1);
  int rem  = lb % (MTX * NT1);
  int mt = rem / NT1, nt = rem % NT1;
  bool isEdge = comp >= 16;
  int k16 = isEdge ? comp - 16 : comp;
  const float* W1 = (isEdge ? eW1 : nW1) + (size_t)k16 * DD * HH;
  const float* b1 = (isEdge ? eb1 : nb1) + (size_t)k16 * HH;

  int tid = threadIdx.x, lane = tid & 63, wid = tid >> 6;
  int wm = (wid >> 1) << 7, wn = (wid & 1) << 6;   // 2x2 waves of 128x64
  int lr = lane & 15, lg = lane >> 4;

  f32x4 acc[8][4] = {};
  kloop<HH>(Ab + ((size_t)(comp * MP + mt * BMX)) * DD,
            W1 + nt * BNX, smem, acc, wm, wn, lr, lg, tid);

  // epilogue: +b1, exact gelu -> Cs (stride 132), then coalesced
  // PRE-SWIZZLED bf16 h store (so hsum_kernel can un-XOR it)
  __builtin_amdgcn_s_barrier();
  short* Cs = smem;                        // 256*132 = 33792 shorts
  const float* b1p = b1 + nt * BNX;
#pragma unroll
  for (int i = 0; i < 8; ++i)
#pragma unroll
    for (int j = 0; j < 4; ++j) {
      int nl = wn + j * 16 + lr;
      float bias = b1p[nl];
#pragma unroll
      for (int rr = 0; rr < 4; ++rr) {
        int ml = wm + i * 16 + lg * 4 + rr;
        float v = acc[i][j][rr] + bias;
        float ge = 0.5f * v * (1.0f + erff(v * 0.70710678118654752f));
        Cs[ml * 132 + nl] = f2bf(ge);
      }
    }
  __syncthreads();
  short* hrow = hbuf + ((size_t)(comp * MP + mt * BMX)) * HH;
#pragma unroll
  for (int q = 0; q < 32; ++q) {
    int gl = q * 256 + tid;
    int r = gl >> 5, gg = gl & 31;         // 32 4-short granules per row
    s16x4 v = *reinterpret_cast<const s16x4*>(&Cs[r * 132 + gg * 4]);
    int dst = (nt * 2 + (gg >> 4)) * 64 + ((((gg >> 1) & 7) ^ swz(r)) << 3) + (gg & 1) * 4;
    *reinterpret_cast<s16x4*>(&hrow[(size_t)r * HH + dst]) = v;
  }
}

// ------------- hsum: hsum[comp][t][k] = sum_{kept rows, seg=t} h[row][k] ---
// 1024 one-wave blocks: comp x 4 col-chunks(512) x 8 row-slices(128 sorted
// rows). Each lane owns 8 FIXED data columns (address un-XORs the swizzle);
// register accumulation; flush on (uniform) t-run boundary via global f32
// atomicAdd (~2-3 flushes per slice).
__global__ __launch_bounds__(64) void hsum_kernel(
    const short* __restrict__ hbuf, const int* __restrict__ perm,
    const int* __restrict__ counts, float* __restrict__ hsum) {
  __shared__ int spre[TT + 1];
  int b = blockIdx.x;
  int comp  = b >> 5;
  int chunk = (b >> 3) & 3;
  int slice = b & 7;
  int g = threadIdx.x;               // 0..63 granule within 512-col chunk
  int cL = g >> 3, gd = g & 7;
  int colBase = (chunk * 8 + cL) * 64 + gd * 8;

  if (g == 0) {
    int s = 0;
    for (int t = 0; t < TT; ++t) { spre[t] = s; s += counts[comp * TT + t]; }
    spre[TT] = s;
  }
  __syncthreads();
  int ntot = spre[TT];
  int i0 = slice * 128;
  if (i0 >= ntot) return;
  int i1 = i0 + 128 < ntot ? i0 + 128 : ntot;

  int t = 0;
  while (i0 >= spre[t + 1]) ++t;     // uniform
  int nextb = spre[t + 1];

  float acc[8] = {};
  float* hcomp = hsum + ((size_t)comp * TT) * HH;
  const short* hb = hbuf + (size_t)comp * MP * HH;
  const int* pcomp = perm + (comp << 10);

#pragma unroll 1
  for (int i = i0; i < i1; ++i) {
    if (i >= nextb) {                // uniform flush on t-run boundary
      float* dst = hcomp + (size_t)t * HH + colBase;
#pragma unroll
      for (int e = 0; e < 8; ++e) { atomicAdd(&dst[e], acc[e]); acc[e] = 0.0f; }
      do { ++t; nextb = spre[t + 1]; } while (i >= nextb);
    }
    int r = pcomp[i];
    const short* src = hb + (size_t)r * HH + (chunk * 8 + cL) * 64 + ((gd ^ swz(r)) << 3);
    bf16x8 v = *reinterpret_cast<const bf16x8*>(src);
#pragma unroll
    for (int e = 0; e < 8; ++e) acc[e] += bf2f(v[e]);
  }
  float* dst = hcomp + (size_t)t * HH + colBase;
#pragma unroll
  for (int e = 0; e < 8; ++e) atomicAdd(&dst[e], acc[e]);
}

// ------------- GEMM3: out = (hsum @ W2 + n_t*b2) / 4096 --------------------
__global__ __launch_bounds__(256) void gemm3_kernel(
    const float* __restrict__ hsum, const int* __restrict__ counts,
    const float* __restrict__ nW2, const float* __restrict__ nb2,
    const float* __restrict__ eW2, const float* __restrict__ eb2,
    float* __restrict__ out) {
  __shared__ float hs[TT * 256];   // 16 KB
  int bid = blockIdx.x;
  int comp = bid >> 3, chunk = bid & 7;
  bool isEdge = comp >= 16;
  int k16 = isEdge ? comp - 16 : comp;
  const float* W2 = (isEdge ? eW2 : nW2) + (size_t)k16 * HH * CC;
  const float* b2 = (isEdge ? eb2 : nb2) + (size_t)k16 * CC;
  int tid = threadIdx.x;
  int col = chunk * 128 + (tid & 127);
  int tg = tid >> 7;                         // 0/1 -> t in [tg*8, tg*8+8)
  float acc[8] = {};
  const float* hbase = hsum + (size_t)comp * TT * HH;

  for (int kb = 0; kb < HH / 256; ++kb) {
    __syncthreads();
    for (int q = 0; q < 16; ++q) {
      int idx = q * 256 + tid;               // 0..4095
      int t = idx >> 8, k = idx & 255;
      hs[t * 256 + k] = hbase[(size_t)t * HH + kb * 256 + k];
    }
    __syncthreads();
#pragma unroll 4
    for (int k = 0; k < 256; ++k) {
      float w = W2[(size_t)(kb * 256 + k) * CC + col];
#pragma unroll
      for (int tt = 0; tt < 8; ++tt)
        acc[tt] += hs[(tg * 8 + tt) * 256 + k] * w;
    }
  }
#pragma unroll
  for (int tt = 0; tt < 8; ++tt) {
    int t = tg * 8 + tt;
    float v = (acc[tt] + (float)counts[comp * TT + t] * b2[col]) * (1.0f / 4096.0f);
    out[(size_t)t * 32768 + comp * 1024 + col] = v;
  }
}

// ---------------------------------------------------------------------------
extern "C" void kernel_launch(void* const* d_in, const int* in_sizes, int n_in,
                              void* d_out, int out_size, void* d_ws, size_t ws_size,
                              hipStream_t stream) {
  const float* x    = (const float*)d_in[0];
  const int*   ridx = (const int*)d_in[3];
  const float* nW1  = (const float*)d_in[4];
  const float* nb1  = (const float*)d_in[5];
  const float* nW2  = (const float*)d_in[6];
  const float* nb2  = (const float*)d_in[7];
  const float* eW1  = (const float*)d_in[8];
  const float* eb1  = (const float*)d_in[9];
  const float* eW2  = (const float*)d_in[10];
  const float* eb2  = (const float*)d_in[11];
  float* out = (float*)d_out;

  // ws: [h 134MB][bitmap 128KB][counts 2KB][perm 128KB][hsum 4MB][Ab 134MB]
  const size_t H_B   = (size_t)NCOMP * MP * HH * 2;
  const size_t BMP_B = (size_t)NCOMP * 1024 * 4;
  const size_t CNT_B = (size_t)NCOMP * TT * 4;
  const size_t PRM_B = (size_t)NCOMP * MP * 4;
  const size_t HS_B  = (size_t)NCOMP * TT * HH * 4;

  char* ws = (char*)d_ws;
  short* hbuf      = (short*)ws;
  unsigned* bitmap = (unsigned*)(ws + H_B);
  int* counts      = (int*)(ws + H_B + BMP_B);
  int* perm        = (int*)(ws + H_B + BMP_B + CNT_B);
  float* hsum      = (float*)(ws + H_B + BMP_B + CNT_B + PRM_B);
  short* Ab        = (short*)(ws + H_B + BMP_B + CNT_B + PRM_B + HS_B);

  hipMemsetAsync(bitmap, 0, BMP_B, stream);
  hipMemsetAsync(hsum, 0, HS_B, stream);
  dedup_kernel<<<NCOMP, 256, 0, stream>>>(ridx, bitmap, perm, counts);
  gather_kernel<<<NCOMP * 128, 256, 0, stream>>>(x, ridx, Ab);
  gemm1_kernel<<<NCOMP * MTX * NT1, 256, 0, stream>>>(nW1, nb1, eW1, eb1, Ab, hbuf);
  hsum_kernel<<<NCOMP * 32, 64, 0, stream>>>(hbuf, perm, counts, hsum);
  gemm3_kernel<<<NCOMP * 8, 256, 0, stream>>>(hsum, counts, nW2, nb2, eW2, eb2, out);
}

// Round 17
// 710.228 us; speedup vs baseline: 2.0754x; 2.0754x over previous
//
#include <hip/hip_runtime.h>
#include <math.h>

// ---------------------------------------------------------------------------
// Disentangler: 32 component-MLPs over sampled token rows + masked seg-pool.
// Round-17 (= r16 with the BW-bound tail properly parallelized):
//   pooled = (sum_{unique r, seg=t} gelu(x_r @ W1 + b1)) @ W2 + n_t*b2
// gemm1: r12-exact (441us proven). hsum: 2048 one-wave blocks stream h in
// t-sorted order (perm from dedup). gemm3: 2048 blocks (comp x 8 col-chunks
// x 8 k-slabs), atomicAdd partials into zero-init'd out. gemm2's 137 GFLOP
// deleted; r16's gemm3 latency bug (256 blocks, 184 GB/s) fixed by 8x split.
// ---------------------------------------------------------------------------

typedef __attribute__((ext_vector_type(8))) short bf16x8;
typedef __attribute__((ext_vector_type(4))) short s16x4;
typedef __attribute__((ext_vector_type(4))) float f32x4;
typedef unsigned int u32;

constexpr int TT    = 16;
constexpr int TOKN  = 4096;
constexpr int DD    = 2048;
constexpr int HH    = 2048;
constexpr int CC    = 1024;
constexpr int LL    = 1000;
constexpr int NCOMP = 32;
constexpr int MP    = 1024;
constexpr int BMX = 256, BNX = 128;
constexpr int MTX  = MP / BMX;    // 4 m-tiles
constexpr int NT1 = HH / BNX;     // 16 n-tiles (gemm1)
constexpr int NT  = DD / 64;      // 32 K-tiles

__device__ __forceinline__ short f2bf(float f) {
  __bf16 h = (__bf16)f;
  return *reinterpret_cast<short*>(&h);
}
__device__ __forceinline__ float bf2f(short s) {
  union { unsigned u; float f; } v;
  v.u = ((unsigned)(unsigned short)s) << 16;
  return v.f;
}
// Row swizzle (period 64): data-granule g of a 64-elem chunk lives at slot
// g ^ swz(row). Identical layout in Ab, h, and the LDS tiles.
__device__ __forceinline__ int swz(int row) {
  return (row & 7) ^ ((row >> 3) & 7);
}
__device__ __forceinline__ int sw(int row, int gran) {   // short offset
  return (row << 6) + ((gran ^ swz(row)) << 3);
}
__device__ __forceinline__ void gl_lds16(const void* g, void* l) {
  __builtin_amdgcn_global_load_lds(
      (const __attribute__((address_space(1))) u32*)g,
      (__attribute__((address_space(3))) u32*)l, 16, 0, 0);
}

// ------------- dedup: keep-mask, per-t counts, t-sorted perm ---------------
__global__ void dedup_kernel(const int* __restrict__ ridx,
                             unsigned* __restrict__ bitmap,
                             int* __restrict__ perm,
                             int* __restrict__ counts) {
  __shared__ int info[MP];       // t (4b) | keep<<8
  __shared__ int cnt[TT];
  __shared__ int base[TT + 1];
  int comp = blockIdx.x;
  if (threadIdx.x < TT) cnt[threadIdx.x] = 0;
  __syncthreads();
  for (int l = threadIdx.x; l < MP; l += 256) {
    int v = 0;
    if (l < LL) {
      int r = ridx[comp * LL + l];
      unsigned bit = 1u << (r & 31);
      unsigned old = atomicOr(&bitmap[(comp << 10) + (r >> 5)], bit);
      int kv = (old & bit) ? 0 : 1;
      if (kv) atomicAdd(&cnt[r >> 11], 1);
      v = (r >> 11) | (kv << 8);
    }
    info[l] = v;
  }
  __syncthreads();
  if (threadIdx.x == 0) {
    int s = 0;
    for (int t = 0; t < TT; ++t) {
      base[t] = s; counts[comp * TT + t] = cnt[t]; s += cnt[t];
    }
    base[TT] = s;
  }
  __syncthreads();
  if (threadIdx.x < TT) {                 // 16 scanners, l-ascending (stable)
    int t = threadIdx.x, off = base[t];
    for (int l = 0; l < MP; ++l) {
      int v = info[l];
      if ((v >> 8) && (v & 15) == t) perm[(comp << 10) + off++] = l;
    }
  }
}

// --------------------------- gather: x rows -> pre-swizzled bf16 -----------
__global__ __launch_bounds__(256) void gather_kernel(
    const float* __restrict__ x, const int* __restrict__ ridx,
    short* __restrict__ Ab) {
  int bid = blockIdx.x;
  int comp = bid >> 7, rgrp = bid & 127;
  int t = threadIdx.x;
  int tr = t >> 5, tn = t & 31;
  int m = rgrp * 8 + tr;
  int mi = m < LL ? m : LL - 1;
  int r = ridx[comp * LL + mi];
  int tokoff = comp >= 16 ? TOKN / 2 : 0;
  const float* src = x + ((size_t)(r >> 11) * TOKN + (r & 2047) + tokoff) * DD;
  short* drow = Ab + ((size_t)(comp * MP + m)) * DD;
  int s_m = swz(m);
#pragma unroll
  for (int i = 0; i < 8; ++i) {
    int gi = tn + 32 * i;
    float4 f0 = *reinterpret_cast<const float4*>(src + gi * 8);
    float4 f1 = *reinterpret_cast<const float4*>(src + gi * 8 + 4);
    bf16x8 pk;
    pk[0]=f2bf(f0.x); pk[1]=f2bf(f0.y); pk[2]=f2bf(f0.z); pk[3]=f2bf(f0.w);
    pk[4]=f2bf(f1.x); pk[5]=f2bf(f1.y); pk[6]=f2bf(f1.z); pk[7]=f2bf(f1.w);
    int c = gi >> 3, g = gi & 7;
    *reinterpret_cast<bf16x8*>(&drow[c * 64 + ((g ^ s_m) << 3)]) = pk;
  }
}

// --------------------------- K-loop (r12, unchanged) -----------------------
template<int LDW>
__device__ __forceinline__ void kloop(
    const short* __restrict__ aBase,   // bf16 pre-swizzled rows, stride 2048
    const float* __restrict__ wBase,   // fp32 W [k][LDW] at col offset nt*BNX
    short* sm, f32x4 (&acc)[8][4],
    int wm, int wn, int lr, int lg, int tid) {
  const short* aSrc0 = aBase + (size_t)(tid >> 3) * 2048 + (tid & 7) * 8;
  int ldsA0 = tid * 8;
  int tn = tid & 31, tkb = tid >> 5, bn0 = tn * 4;
  const float* wCol = wBase + bn0;

  float4 brB[8];

  auto aglds = [&](int t, int buf) {
    short* l = sm + buf * 16384;
#pragma unroll
    for (int q = 0; q < 8; ++q)
      gl_lds16(aSrc0 + (size_t)q * 65536 + t * 64, l + ldsA0 + q * 2048);
  };
  auto bload = [&](int t) {
    const float* bb = wCol + (size_t)(t * 64 + tkb * 8) * LDW;
#pragma unroll
    for (int i = 0; i < 8; ++i)
      brB[i] = *reinterpret_cast<const float4*>(bb + (size_t)i * LDW);
  };
  auto bwrite = [&]() {
    short* Bs = sm + 32768;
#pragma unroll
    for (int j = 0; j < 4; ++j) {
      bf16x8 pk;
#pragma unroll
      for (int i = 0; i < 8; ++i) pk[i] = f2bf((&brB[i].x)[j]);
      *reinterpret_cast<bf16x8*>(&Bs[sw(bn0 + j, tkb)]) = pk;
    }
  };
  auto compute = [&](int d) {
    const short* A = sm + d * 16384;
    const short* B = sm + 32768;
#pragma unroll
    for (int kk = 0; kk < 2; ++kk) {
      bf16x8 af[8], bfr[4];
#pragma unroll
      for (int i = 0; i < 8; ++i)
        af[i] = *reinterpret_cast<const bf16x8*>(&A[sw(wm + i * 16 + lr, kk * 4 + lg)]);
#pragma unroll
      for (int j = 0; j < 4; ++j)
        bfr[j] = *reinterpret_cast<const bf16x8*>(&B[sw(wn + j * 16 + lr, kk * 4 + lg)]);
      __builtin_amdgcn_s_setprio(1);
#pragma unroll
      for (int i = 0; i < 8; ++i)
#pragma unroll
        for (int j = 0; j < 4; ++j)
          acc[i][j] = __builtin_amdgcn_mfma_f32_16x16x32_bf16(af[i], bfr[j], acc[i][j], 0, 0, 0);
      __builtin_amdgcn_s_setprio(0);
    }
  };

  bload(0);
  aglds(0, 0);
  bwrite();
  bload(1);
  aglds(1, 1);
  asm volatile("s_waitcnt lgkmcnt(0)" ::: "memory");
  __builtin_amdgcn_s_barrier();

#pragma unroll 1
  for (int t = 0; t < NT; ++t) {
    if (t < NT - 1) {
      asm volatile("s_waitcnt vmcnt(16)" ::: "memory");  // A(t) landed
    } else {
      asm volatile("s_waitcnt vmcnt(0)" ::: "memory");
    }
    __builtin_amdgcn_sched_barrier(0);
    compute(t & 1);
    __builtin_amdgcn_s_barrier();          // all waves done reading A(t), B(t)
    if (t + 1 < NT) {
      bwrite();                            // B(t+1) -> Bbuf (vmcnt(8) auto)
      if (t + 2 < NT) {
        bload(t + 2);                      // issued BEFORE aglds (ordering!)
        aglds(t + 2, t & 1);
      }
      asm volatile("s_waitcnt lgkmcnt(0)" ::: "memory");
      __builtin_amdgcn_s_barrier();
    }
  }
}

// --------------------------- GEMM1: h = gelu(x_sel @ W1 + b1) --------------
__global__ __launch_bounds__(256, 2) void gemm1_kernel(
    const float* __restrict__ nW1, const float* __restrict__ nb1,
    const float* __restrict__ eW1, const float* __restrict__ eb1,
    const short* __restrict__ Ab, short* __restrict__ hbuf) {
  __shared__ short smem[40960];   // 80 KB

  constexpr int NWG = NCOMP * MTX * NT1;   // 2048
  constexpr int CPX = NWG / 8;
  int b0 = blockIdx.x;
  int lb = (b0 & 7) * CPX + (b0 >> 3);     // XCD-chunked (T1), bijective
  int comp = lb / (MTX * NT1);
  int rem  = lb % (MTX * NT1);
  int mt = rem / NT1, nt = rem % NT1;
  bool isEdge = comp >= 16;
  int k16 = isEdge ? comp - 16 : comp;
  const float* W1 = (isEdge ? eW1 : nW1) + (size_t)k16 * DD * HH;
  const float* b1 = (isEdge ? eb1 : nb1) + (size_t)k16 * HH;

  int tid = threadIdx.x, lane = tid & 63, wid = tid >> 6;
  int wm = (wid >> 1) << 7, wn = (wid & 1) << 6;   // 2x2 waves of 128x64
  int lr = lane & 15, lg = lane >> 4;

  f32x4 acc[8][4] = {};
  kloop<HH>(Ab + ((size_t)(comp * MP + mt * BMX)) * DD,
            W1 + nt * BNX, smem, acc, wm, wn, lr, lg, tid);

  // epilogue: +b1, exact gelu -> Cs (stride 132), then coalesced
  // PRE-SWIZZLED bf16 h store (so hsum_kernel can un-XOR it)
  __builtin_amdgcn_s_barrier();
  short* Cs = smem;                        // 256*132 = 33792 shorts
  const float* b1p = b1 + nt * BNX;
#pragma unroll
  for (int i = 0; i < 8; ++i)
#pragma unroll
    for (int j = 0; j < 4; ++j) {
      int nl = wn + j * 16 + lr;
      float bias = b1p[nl];
#pragma unroll
      for (int rr = 0; rr < 4; ++rr) {
        int ml = wm + i * 16 + lg * 4 + rr;
        float v = acc[i][j][rr] + bias;
        float ge = 0.5f * v * (1.0f + erff(v * 0.70710678118654752f));
        Cs[ml * 132 + nl] = f2bf(ge);
      }
    }
  __syncthreads();
  short* hrow = hbuf + ((size_t)(comp * MP + mt * BMX)) * HH;
#pragma unroll
  for (int q = 0; q < 32; ++q) {
    int gl = q * 256 + tid;
    int r = gl >> 5, gg = gl & 31;         // 32 4-short granules per row
    s16x4 v = *reinterpret_cast<const s16x4*>(&Cs[r * 132 + gg * 4]);
    int dst = (nt * 2 + (gg >> 4)) * 64 + ((((gg >> 1) & 7) ^ swz(r)) << 3) + (gg & 1) * 4;
    *reinterpret_cast<s16x4*>(&hrow[(size_t)r * HH + dst]) = v;
  }
}

// ------------- hsum: hsum[comp][t][k] = sum_{kept rows, seg=t} h[row][k] ---
// 2048 one-wave blocks: comp x 4 col-chunks(512) x 16 row-slices(64 sorted
// rows). Each lane owns 8 FIXED data columns (address un-XORs the swizzle);
// register accumulation; flush on (uniform) t-run boundary via global f32
// atomicAdd.
__global__ __launch_bounds__(64) void hsum_kernel(
    const short* __restrict__ hbuf, const int* __restrict__ perm,
    const int* __restrict__ counts, float* __restrict__ hsum) {
  __shared__ int spre[TT + 1];
  int b = blockIdx.x;
  int comp  = b >> 6;
  int chunk = (b >> 4) & 3;
  int slice = b & 15;
  int g = threadIdx.x;               // 0..63 granule within 512-col chunk
  int cL = g >> 3, gd = g & 7;
  int colBase = (chunk * 8 + cL) * 64 + gd * 8;

  if (g == 0) {
    int s = 0;
    for (int t = 0; t < TT; ++t) { spre[t] = s; s += counts[comp * TT + t]; }
    spre[TT] = s;
  }
  __syncthreads();
  int ntot = spre[TT];
  int i0 = slice * 64;
  if (i0 >= ntot) return;
  int i1 = i0 + 64 < ntot ? i0 + 64 : ntot;

  int t = 0;
  while (i0 >= spre[t + 1]) ++t;     // uniform
  int nextb = spre[t + 1];

  float acc[8] = {};
  float* hcomp = hsum + ((size_t)comp * TT) * HH;
  const short* hb = hbuf + (size_t)comp * MP * HH;
  const int* pcomp = perm + (comp << 10);

#pragma unroll 1
  for (int i = i0; i < i1; ++i) {
    if (i >= nextb) {                // uniform flush on t-run boundary
      float* dst = hcomp + (size_t)t * HH + colBase;
#pragma unroll
      for (int e = 0; e < 8; ++e) { atomicAdd(&dst[e], acc[e]); acc[e] = 0.0f; }
      do { ++t; nextb = spre[t + 1]; } while (i >= nextb);
    }
    int r = pcomp[i];
    const short* src = hb + (size_t)r * HH + (chunk * 8 + cL) * 64 + ((gd ^ swz(r)) << 3);
    bf16x8 v = *reinterpret_cast<const bf16x8*>(src);
#pragma unroll
    for (int e = 0; e < 8; ++e) acc[e] += bf2f(v[e]);
  }
  float* dst = hcomp + (size_t)t * HH + colBase;
#pragma unroll
  for (int e = 0; e < 8; ++e) atomicAdd(&dst[e], acc[e]);
}

// ------------- GEMM3: out += (hsum_kslab @ W2_kslab) / 4096 ----------------
// 2048 blocks: comp(32) x col-chunk(8, 128 cols) x k-slab(8, 256 k).
// kslab 0 also adds the n_t*b2 bias term. out must be zero-init'd.
__global__ __launch_bounds__(256) void gemm3_kernel(
    const float* __restrict__ hsum, const int* __restrict__ counts,
    const float* __restrict__ nW2, const float* __restrict__ nb2,
    const float* __restrict__ eW2, const float* __restrict__ eb2,
    float* __restrict__ out) {
  __shared__ float hs[TT * 256];   // 16 KB
  int bid = blockIdx.x;
  int comp = bid >> 6;
  int rem  = bid & 63;
  int chunk = rem >> 3, ks = rem & 7;
  bool isEdge = comp >= 16;
  int k16 = isEdge ? comp - 16 : comp;
  const float* W2 = (isEdge ? eW2 : nW2) + (size_t)k16 * HH * CC;
  const float* b2 = (isEdge ? eb2 : nb2) + (size_t)k16 * CC;
  int tid = threadIdx.x;
  int col = chunk * 128 + (tid & 127);
  int tg = tid >> 7;                         // 0/1 -> t in [tg*8, tg*8+8)
  float acc[8] = {};
  const float* hbase = hsum + (size_t)comp * TT * HH + ks * 256;

  // stage hsum[16][256] for this k-slab
  for (int q = 0; q < 16; ++q) {
    int idx = q * 256 + tid;                 // 0..4095
    int t = idx >> 8, k = idx & 255;
    hs[t * 256 + k] = hbase[(size_t)t * HH + k];
  }
  __syncthreads();
  const float* wb = W2 + (size_t)ks * 256 * CC + col;
#pragma unroll 8
  for (int k = 0; k < 256; ++k) {
    float w = wb[(size_t)k * CC];
#pragma unroll
    for (int tt = 0; tt < 8; ++tt)
      acc[tt] += hs[(tg * 8 + tt) * 256 + k] * w;
  }
#pragma unroll
  for (int tt = 0; tt < 8; ++tt) {
    int t = tg * 8 + tt;
    float v = acc[tt] * (1.0f / 4096.0f);
    if (ks == 0)
      v += (float)counts[comp * TT + t] * b2[col] * (1.0f / 4096.0f);
    atomicAdd(&out[(size_t)t * 32768 + comp * 1024 + col], v);
  }
}

// ---------------------------------------------------------------------------
extern "C" void kernel_launch(void* const* d_in, const int* in_sizes, int n_in,
                              void* d_out, int out_size, void* d_ws, size_t ws_size,
                              hipStream_t stream) {
  const float* x    = (const float*)d_in[0];
  const int*   ridx = (const int*)d_in[3];
  const float* nW1  = (const float*)d_in[4];
  const float* nb1  = (const float*)d_in[5];
  const float* nW2  = (const float*)d_in[6];
  const float* nb2  = (const float*)d_in[7];
  const float* eW1  = (const float*)d_in[8];
  const float* eb1  = (const float*)d_in[9];
  const float* eW2  = (const float*)d_in[10];
  const float* eb2  = (const float*)d_in[11];
  float* out = (float*)d_out;

  // ws: [h 134MB][bitmap 128KB][counts 2KB][perm 128KB][hsum 4MB][Ab 134MB]
  const size_t H_B   = (size_t)NCOMP * MP * HH * 2;
  const size_t BMP_B = (size_t)NCOMP * 1024 * 4;
  const size_t CNT_B = (size_t)NCOMP * TT * 4;
  const size_t PRM_B = (size_t)NCOMP * MP * 4;
  const size_t HS_B  = (size_t)NCOMP * TT * HH * 4;

  char* ws = (char*)d_ws;
  short* hbuf      = (short*)ws;
  unsigned* bitmap = (unsigned*)(ws + H_B);
  int* counts      = (int*)(ws + H_B + BMP_B);
  int* perm        = (int*)(ws + H_B + BMP_B + CNT_B);
  float* hsum      = (float*)(ws + H_B + BMP_B + CNT_B + PRM_B);
  short* Ab        = (short*)(ws + H_B + BMP_B + CNT_B + PRM_B + HS_B);

  hipMemsetAsync(bitmap, 0, BMP_B, stream);
  hipMemsetAsync(hsum, 0, HS_B, stream);
  hipMemsetAsync(out, 0, (size_t)out_size * sizeof(float), stream);
  dedup_kernel<<<NCOMP, 256, 0, stream>>>(ridx, bitmap, perm, counts);
  gather_kernel<<<NCOMP * 128, 256, 0, stream>>>(x, ridx, Ab);
  gemm1_kernel<<<NCOMP * MTX * NT1, 256, 0, stream>>>(nW1, nb1, eW1, eb1, Ab, hbuf);
  hsum_kernel<<<NCOMP * 64, 64, 0, stream>>>(hbuf, perm, counts, hsum);
  gemm3_kernel<<<NCOMP * 64, 256, 0, stream>>>(hsum, counts, nW2, nb2, eW2, eb2, out);
}